// Round 18
// baseline (5778.062 us; speedup 1.0000x reference)
//
#include <hip/hip_runtime.h>

typedef unsigned short ushort_t;
typedef unsigned int   uint_t;
typedef unsigned long long u64;
using bf16x8 = __attribute__((ext_vector_type(8))) short;
using f32x4  = __attribute__((ext_vector_type(4))) float;
using f32x2  = __attribute__((ext_vector_type(2))) float;

// T=256, B=128, H=512, E=256, IN=512, D=1024, 3H=1536.  ALL float I/O is FP32.

__device__ __forceinline__ float bf2f(ushort_t u) {
  union { uint_t i; float f; } v; v.i = ((uint_t)u) << 16; return v.f;
}
__device__ __forceinline__ ushort_t f2bf(float f) {
  union { float f; uint_t i; } v; v.f = f;
  uint_t r = v.i + 0x7fffu + ((v.i >> 16) & 1u);
  return (ushort_t)(r >> 16);
}
__device__ __forceinline__ float scrub(float x) {
  union { float f; uint_t i; } v; v.f = x;
  return ((v.i & 0x7f800000u) == 0x7f800000u) ? 0.f : x;
}
__device__ __forceinline__ float sclamp(float x) {
  float y = scrub(x);
  return fminf(30.f, fmaxf(-30.f, y));
}
__device__ __forceinline__ float sigm(float x) { return 1.f / (1.f + __expf(-x)); }
__device__ __forceinline__ float tanh_f(float x) {
  float t = __expf(-2.f * fabsf(x));
  float r = (1.f - t) / (1.f + t);
  return x < 0.f ? -r : r;
}
// load 8 f32 and convert to bf16x8 (RNE)
__device__ __forceinline__ bf16x8 cvt8(const float* __restrict__ p) {
  f32x4 u0 = *(const f32x4*)p;
  f32x4 u1 = *(const f32x4*)(p + 4);
  bf16x8 r;
  #pragma unroll
  for (int j = 0; j < 4; ++j) { r[j] = (short)f2bf(u0[j]); r[j+4] = (short)f2bf(u1[j]); }
  return r;
}

// ---------------- zero-fill ----------------
__global__ __launch_bounds__(256) void zero_kernel(uint_t* __restrict__ p, int n32) {
  int i = blockIdx.x * 256 + threadIdx.x;
  if (i < n32) p[i] = 0;
}

// ---------------- init h2 (hi|lo packed bf16 split of f32 state), both parities ----------------
__global__ __launch_bounds__(256) void init_kernel(
    const float* __restrict__ state, uint_t* __restrict__ h2) {
  int i = blockIdx.x * 256 + threadIdx.x;   // 0..131071 over (2,128,512)
  float v = state[i];
  ushort_t hi = f2bf(v);
  ushort_t lo = f2bf(v - bf2f(hi));
  uint_t packed = ((uint_t)hi << 16) | (uint_t)lo;
  int dirp = i >> 16;
  int rem  = i & 65535;
  h2[(size_t)(dirp * 2 + 0) * 65536 + rem] = packed;
  h2[(size_t)(dirp * 2 + 1) * 65536 + rem] = packed;
}

// ---------------- transpose W_att (f32 1024x1024) -> WattT bf16 [j][d] ----------------
__global__ __launch_bounds__(256) void transpose_kernel(
    const float* __restrict__ W, ushort_t* __restrict__ WT) {
  __shared__ float tile[32][33];
  int bx = blockIdx.x & 31, by = blockIdx.x >> 5;
  int r0 = by * 32, c0 = bx * 32;
  int tid = threadIdx.x;
  int r = tid >> 3, c4 = (tid & 7) * 4;
  #pragma unroll
  for (int i = 0; i < 4; ++i) tile[r][c4 + i] = W[(size_t)(r0 + r) * 1024 + c0 + c4 + i];
  __syncthreads();
  int jr = tid >> 3, d4 = (tid & 7) * 4;
  #pragma unroll
  for (int i = 0; i < 4; ++i)
    WT[(size_t)(c0 + jr) * 1024 + r0 + d4 + i] = f2bf(tile[d4 + i][jr]);
}

// ---------------- the recurrent kernel (dual independent chains per SIMD) ----------------
// grid = 128 blocks (bi = wg*2 + dir; wg 0..63 owns 8 h-cols), 512 threads (8 waves).
// Wave = grp*4 + rg: rows [grp*64+rg*16,+16) x cols [wg*8,+8), FULL k=512, x+h GEMMs,
// elementwise, release -- all per-wave, NO intra-block barriers after weight staging.
// Each SIMD hosts one grp0 + one grp1 wave whose chains are INDEPENDENT; grp1 gets a
// ~7us start skew (s_sleep) so the chains run in anti-phase: one chain's poll-wait
// hides under the other's compute (R17 showed ~88% idle with correlated stalls).
// 24 gate rows covered by two overlapping 16-col MFMA tiles; per-lane gate regroup
// via 3 shfl_xor(8). Gates r,z merge x+h in acc0; n keeps x/h split (acc1x/acc1h).
// Chains: [2dir][2grp][4rg] x 64 producer flags. Protocol = proven R12/R17 scheme.
__global__ __launch_bounds__(512, 2) void rnn_kernel(
    const int* __restrict__ tim_seq, const int* __restrict__ loc_seq,
    const float* __restrict__ emb_tim, const float* __restrict__ emb_loc,
    const float* __restrict__ state,        // [2][128][512] f32 (h0)
    uint_t* __restrict__ h2,                // [2dir][2par][128][512] u32 (hi|lo)
    const float* __restrict__ Wih_f, const float* __restrict__ Whh_f,
    const float* __restrict__ bih_f, const float* __restrict__ bhh_f,
    const float* __restrict__ Wih_b, const float* __restrict__ Whh_b,
    const float* __restrict__ bih_b, const float* __restrict__ bhh_b,
    ushort_t* __restrict__ output,          // [256][128][1024] bf16 (intermediate)
    float* __restrict__ state_out,          // d_out + 131072 : [2][128][512] f32
    uint_t* __restrict__ flags)             // [16][64] per-chain step flags
{
  __shared__ __align__(16) ushort_t Wxh[24 * 512];     // Wih hi      24,576 B
  __shared__ __align__(16) ushort_t Whi[24 * 512];     // Whh hi      24,576 B
  __shared__ __align__(16) ushort_t Wlo[24 * 512];     // Whh lo      24,576 B
  __shared__ float bias_l[6][8];                       //    192 B

  const int tid  = threadIdx.x;
  const int lane = tid & 63;
  const int wave = tid >> 6;           // 0..7
  const int rg   = wave & 3;           // row group
  const int grp  = wave >> 2;          // batch group (independent chain)
  const int bi   = blockIdx.x;
  const int dir  = bi & 1;
  const int wg   = bi >> 1;            // 0..63, owns cols [wg*8, wg*8+8)
  const int b0   = grp * 64;
  uint_t* chain_flags = flags + (((dir * 2 + grp) * 4 + rg) * 64);

  const float* Wih = dir ? Wih_b : Wih_f;
  const float* Whh = dir ? Whh_b : Whh_f;
  const float* bih = dir ? bih_b : bih_f;
  const float* bhh = dir ? bhh_b : bhh_f;

  // stage weights (shared by both grps): Wih->hi; Whh->hi+lo. XOR-swizzled k.
  for (int c = tid; c < 3072; c += 512) {   // 2 mats * 24 rows * 64 chunks
    int m = c >= 1536 ? 1 : 0;
    int cc = c - m * 1536;
    int gcl = cc >> 6;                      // 0..23 local gate row
    int k8  = (cc & 63) << 3;
    int grow = (gcl >> 3) * 512 + wg * 8 + (gcl & 7);
    const float* src = (m ? Whh : Wih) + (size_t)grow * 512 + k8;
    f32x4 u0 = *(const f32x4*)src;
    f32x4 u1 = *(const f32x4*)(src + 4);
    bf16x8 hi8, lo8;
    #pragma unroll
    for (int j = 0; j < 8; ++j) {
      float v = j < 4 ? u0[j] : u1[j - 4];
      ushort_t h = f2bf(v);
      hi8[j] = (short)h;
      lo8[j] = (short)f2bf(v - bf2f(h));
    }
    int dst = gcl * 512 + (k8 ^ ((gcl & 7) << 3));
    if (m) { *(bf16x8*)&Whi[dst] = hi8; *(bf16x8*)&Wlo[dst] = lo8; }
    else   { *(bf16x8*)&Wxh[dst] = hi8; }
  }
  if (tid < 48) {
    int m  = tid / 24;                 // 0: bih, 1: bhh
    int gg = (tid % 24) / 8;           // gate r/z/n
    int c  = tid & 7;
    const float* bb = m ? bhh : bih;
    bias_l[m * 3 + gg][c] = bb[gg * 512 + wg * 8 + c];
  }

  const int rlane = lane & 15;
  const int klb   = (lane >> 4) * 8;
  const int qrow  = (lane >> 4) * 4;
  const int arow  = b0 + rg * 16 + rlane;
  const int swz   = (rlane & 7) << 3;
  const int col   = rlane;             // valid when rlane < 8

  float hp[4] = {0.f, 0.f, 0.f, 0.f};
  if (rlane < 8) {
    #pragma unroll
    for (int q = 0; q < 4; ++q)
      hp[q] = state[(size_t)dir * 65536 + (size_t)(b0 + rg * 16 + qrow + q) * 512 +
                    wg * 8 + col];
  }
  __syncthreads();   // weights staged (the only block barrier)

  // anti-phase skew: grp1 chains start ~half a step later and stay offset
  if (grp == 1) {
    __builtin_amdgcn_s_sleep(127);
    __builtin_amdgcn_s_sleep(127);
  }

  // ---- prefetch next-step x rows as bf16 (full k: kk<8 tim, kk>=8 loc) ----
  bf16x8 px[16];
  {
    const int td0 = dir ? 255 : 0;
    const float* tA = emb_tim + (size_t)tim_seq[td0 * 128 + arow] * 256;
    const float* lA = emb_loc + (size_t)loc_seq[td0 * 128 + arow] * 256;
    #pragma unroll
    for (int kk = 0; kk < 16; ++kk) {
      int k = kk * 32 + klb;
      px[kk] = (kk < 8) ? cvt8(tA + k) : cvt8(lA + (k - 256));
    }
  }

  uint_t pv = 0u;                      // persistent poll register (all 64 lanes)

  for (int t = 0; t < 256; ++t) {
    const int td  = dir ? (255 - t) : t;
    const int par = t & 1;

    f32x4 acc0  = {0.f, 0.f, 0.f, 0.f};   // tile ct0 (gate rows 0-15: r, z), x+h merged
    f32x4 acc1x = {0.f, 0.f, 0.f, 0.f};   // tile ct1 (gate rows 8-23: zdup, n), x part
    f32x4 acc1h = {0.f, 0.f, 0.f, 0.f};   // tile ct1, h part

    // ---- 1. x-MFMA from prefetched bf16 registers ----
    #pragma unroll
    for (int kk = 0; kk < 16; ++kk) {
      int k = kk * 32 + klb;
      int o0 = (0 * 8 + rlane) * 512 + (k ^ swz);
      int o1 = (1 * 8 + rlane) * 512 + (k ^ swz);
      acc0  = __builtin_amdgcn_mfma_f32_16x16x32_bf16(px[kk], *(const bf16x8*)&Wxh[o0], acc0,  0, 0, 0);
      acc1x = __builtin_amdgcn_mfma_f32_16x16x32_bf16(px[kk], *(const bf16x8*)&Wxh[o1], acc1x, 0, 0, 0);
    }

    // ---- 2. issue next step's gather prefetch (overlaps poll + h phase) ----
    if (t < 255) {
      const int tdn = dir ? (255 - (t + 1)) : (t + 1);
      const float* tA = emb_tim + (size_t)tim_seq[tdn * 128 + arow] * 256;
      const float* lA = emb_loc + (size_t)loc_seq[tdn * 128 + arow] * 256;
      #pragma unroll
      for (int kk = 0; kk < 16; ++kk) {
        int k = kk * 32 + klb;
        px[kk] = (kk < 8) ? cvt8(tA + k) : cvt8(lA + (k - 256));
      }
    }

    // ---- 3. poll own chain's 64 flags (full-wave load, persistent early-check) ----
    while (!__all(pv >= (uint_t)t)) {
      pv = __hip_atomic_load(&chain_flags[lane], __ATOMIC_RELAXED,
                             __HIP_MEMORY_SCOPE_AGENT);
      if (__all(pv >= (uint_t)t)) break;
      __builtin_amdgcn_s_sleep(2);
    }
    asm volatile("" ::: "memory");

    // ---- 4. h-loads + h-MFMA (full k; split h hi+lo x Whh hi+lo) ----
    {
      const u64* hrow = (const u64*)(h2 + (size_t)(dir * 2 + par) * 65536 +
                                     (size_t)arow * 512);
      #pragma unroll
      for (int kk = 0; kk < 16; ++kk) {
        int k = kk * 32 + klb;
        u64 q0 = __hip_atomic_load(hrow + (k >> 1),     __ATOMIC_RELAXED, __HIP_MEMORY_SCOPE_AGENT);
        u64 q1 = __hip_atomic_load(hrow + (k >> 1) + 1, __ATOMIC_RELAXED, __HIP_MEMORY_SCOPE_AGENT);
        u64 q2 = __hip_atomic_load(hrow + (k >> 1) + 2, __ATOMIC_RELAXED, __HIP_MEMORY_SCOPE_AGENT);
        u64 q3 = __hip_atomic_load(hrow + (k >> 1) + 3, __ATOMIC_RELAXED, __HIP_MEMORY_SCOPE_AGENT);
        uint_t w[8] = { (uint_t)q0, (uint_t)(q0 >> 32), (uint_t)q1, (uint_t)(q1 >> 32),
                        (uint_t)q2, (uint_t)(q2 >> 32), (uint_t)q3, (uint_t)(q3 >> 32) };
        bf16x8 ahi, alo;
        #pragma unroll
        for (int j = 0; j < 8; ++j) {
          ahi[j] = (short)(w[j] >> 16);
          alo[j] = (short)(w[j] & 0xffffu);
        }
        int o0 = (0 * 8 + rlane) * 512 + (k ^ swz);
        int o1 = (1 * 8 + rlane) * 512 + (k ^ swz);
        bf16x8 bh0 = *(const bf16x8*)&Whi[o0], bl0 = *(const bf16x8*)&Wlo[o0];
        bf16x8 bh1 = *(const bf16x8*)&Whi[o1], bl1 = *(const bf16x8*)&Wlo[o1];
        acc0  = __builtin_amdgcn_mfma_f32_16x16x32_bf16(ahi, bh0, acc0,  0, 0, 0);
        acc0  = __builtin_amdgcn_mfma_f32_16x16x32_bf16(alo, bh0, acc0,  0, 0, 0);
        acc0  = __builtin_amdgcn_mfma_f32_16x16x32_bf16(ahi, bl0, acc0,  0, 0, 0);
        acc1h = __builtin_amdgcn_mfma_f32_16x16x32_bf16(ahi, bh1, acc1h, 0, 0, 0);
        acc1h = __builtin_amdgcn_mfma_f32_16x16x32_bf16(alo, bh1, acc1h, 0, 0, 0);
        acc1h = __builtin_amdgcn_mfma_f32_16x16x32_bf16(ahi, bl1, acc1h, 0, 0, 0);
      }
    }

    // ---- 5. gate regroup via shfl_xor(8), elementwise on rlane<8 ----
    ushort_t hh_out[4];
    {
      #pragma unroll
      for (int q = 0; q < 4; ++q) {
        float zq  = __shfl_xor(acc0[q],  8, 64);   // ct0 col c+8 = gate z
        float nxq = __shfl_xor(acc1x[q], 8, 64);   // ct1 col c+8 = gate n (x part)
        float nhq = __shfl_xor(acc1h[q], 8, 64);   // ct1 col c+8 = gate n (h part)
        if (rlane < 8) {
          float r = sigm(sclamp(acc0[q] + bias_l[0][col] + bias_l[3][col]));
          float z = sigm(sclamp(zq      + bias_l[1][col] + bias_l[4][col]));
          float n = tanh_f(sclamp(nxq + bias_l[2][col]) +
                           r * sclamp(nhq + bias_l[5][col]));
          float hn = (1.f - z) * n + z * hp[q];
          hp[q] = hn;
          ushort_t hh = f2bf(hn);
          ushort_t hl = f2bf(hn - bf2f(hh));
          hh_out[q] = hh;
          int row = b0 + rg * 16 + qrow + q;
          __hip_atomic_store(&h2[(size_t)(dir * 2 + (par ^ 1)) * 65536 +
                                 (size_t)row * 512 + wg * 8 + col],
                             ((uint_t)hh << 16) | (uint_t)hl,
                             __ATOMIC_RELAXED, __HIP_MEMORY_SCOPE_AGENT);
        }
      }
    }

    // ---- 6. lean release: drain h2 stores, flag, THEN output stores ----
    asm volatile("s_waitcnt vmcnt(0)" ::: "memory");
    if (t < 255 && lane == 0) {
      __hip_atomic_store(&chain_flags[wg], (uint_t)(t + 1),
                         __ATOMIC_RELAXED, __HIP_MEMORY_SCOPE_AGENT);
    }
    asm volatile("" ::: "memory");

    if (rlane < 8) {
      #pragma unroll
      for (int q = 0; q < 4; ++q) {
        int row = b0 + rg * 16 + qrow + q;
        output[(size_t)td * 131072 + (size_t)row * 1024 + dir * 512 + wg * 8 + col] =
            hh_out[q];
        if (t == 255) {
          state_out[(size_t)dir * 65536 + (size_t)row * 512 + wg * 8 + col] = hp[q];
        }
      }
    }
  }
}

// ---------------- fused attention scores ----------------
__global__ __launch_bounds__(256) void score_kernel(
    const ushort_t* __restrict__ output,   // [32768][1024] bf16
    const ushort_t* __restrict__ WattT,    // [1024][1024] bf16 (j, d)
    const float* __restrict__ b_att, const float* __restrict__ w_proj,
    float* __restrict__ scores)            // [128][256]
{
  __shared__ __align__(16) ushort_t bst[2][128][72];
  __shared__ float scl[128];
  const int tid = threadIdx.x, lane = tid & 63, wave = tid >> 6;
  const int tb0 = blockIdx.x * 128;
  if (tid < 128) scl[tid] = 0.f;
  __syncthreads();

  const int rlane = lane & 15;
  const int kbase = (lane >> 4) * 8;
  const int sjrow = tid >> 2;
  const int sq8   = (tid & 3) * 8;

  for (int jc = 0; jc < 8; ++jc) {
    f32x4 acc[2][8];
    #pragma unroll
    for (int rt = 0; rt < 2; ++rt)
      #pragma unroll
      for (int ct = 0; ct < 8; ++ct) acc[rt][ct] = (f32x4){0.f, 0.f, 0.f, 0.f};

    {
      const size_t base = (size_t)(jc * 128) * 1024 + sq8;
      *(bf16x8*)&bst[0][sjrow][sq8] = *(const bf16x8*)(WattT + base + (size_t)sjrow * 1024);
      *(bf16x8*)&bst[0][sjrow + 64][sq8] = *(const bf16x8*)(WattT + base + (size_t)(sjrow + 64) * 1024);
    }
    __syncthreads();

    for (int kc = 0; kc < 32; ++kc) {
      if (kc < 31) {
        const size_t base = (size_t)(jc * 128) * 1024 + (size_t)(kc + 1) * 32 + sq8;
        *(bf16x8*)&bst[(kc + 1) & 1][sjrow][sq8] =
            *(const bf16x8*)(WattT + base + (size_t)sjrow * 1024);
        *(bf16x8*)&bst[(kc + 1) & 1][sjrow + 64][sq8] =
            *(const bf16x8*)(WattT + base + (size_t)(sjrow + 64) * 1024);
      }
      int r0 = wave * 32 + rlane;
      int k = kc * 32 + kbase;
      bf16x8 a0 = *(const bf16x8*)(output + (size_t)(tb0 + r0) * 1024 + k);
      bf16x8 a1 = *(const bf16x8*)(output + (size_t)(tb0 + r0 + 16) * 1024 + k);
      int buf = kc & 1;
      #pragma unroll
      for (int ct = 0; ct < 8; ++ct) {
        bf16x8 b = *(const bf16x8*)&bst[buf][ct * 16 + rlane][kbase];
        acc[0][ct] = __builtin_amdgcn_mfma_f32_16x16x32_bf16(a0, b, acc[0][ct], 0, 0, 0);
        acc[1][ct] = __builtin_amdgcn_mfma_f32_16x16x32_bf16(a1, b, acc[1][ct], 0, 0, 0);
      }
      __syncthreads();
    }

    float s[2][4] = {{0.f, 0.f, 0.f, 0.f}, {0.f, 0.f, 0.f, 0.f}};
    #pragma unroll
    for (int ct = 0; ct < 8; ++ct) {
      int j = jc * 128 + ct * 16 + rlane;
      float bv = b_att[j];
      float wv = w_proj[j];
      #pragma unroll
      for (int rt = 0; rt < 2; ++rt)
        #pragma unroll
        for (int q = 0; q < 4; ++q)
          s[rt][q] += tanh_f(sclamp(acc[rt][ct][q] + bv)) * wv;
    }
    #pragma unroll
    for (int rt = 0; rt < 2; ++rt)
      #pragma unroll
      for (int q = 0; q < 4; ++q) {
        float v = s[rt][q];
        v += __shfl_xor(v, 1, 64);
        v += __shfl_xor(v, 2, 64);
        v += __shfl_xor(v, 4, 64);
        v += __shfl_xor(v, 8, 64);
        if ((lane & 15) == 0)
          scl[wave * 32 + rt * 16 + (lane >> 4) * 4 + q] += v;
      }
  }
  __syncthreads();
  if (tid < 128) {
    int tb = tb0 + tid;
    scores[(size_t)(tb & 127) * 256 + (tb >> 7)] = scrub(scl[tid]);
  }
}

// ---------------- softmax over t per batch row (f32 out) ----------------
__global__ __launch_bounds__(256) void softmax_kernel(
    const float* __restrict__ scores, float* __restrict__ attn_out) {
  __shared__ float red[4];
  int b = blockIdx.x, tid = threadIdx.x, lane = tid & 63, wave = tid >> 6;
  float v = scrub(scores[(size_t)b * 256 + tid]);
  float mx = v;
  #pragma unroll
  for (int o = 1; o < 64; o <<= 1) mx = fmaxf(mx, __shfl_xor(mx, o, 64));
  if (lane == 0) red[wave] = mx;
  __syncthreads();
  mx = fmaxf(fmaxf(red[0], red[1]), fmaxf(red[2], red[3]));
  float e = __expf(v - mx);
  float s = e;
  #pragma unroll
  for (int o = 1; o < 64; o <<= 1) s += __shfl_xor(s, o, 64);
  __syncthreads();
  if (lane == 0) red[wave] = s;
  __syncthreads();
  s = red[0] + red[1] + red[2] + red[3];
  attn_out[(size_t)b * 256 + tid] = e / s;
}

// ---------------- pooled[b][d] = sum_t attn[b][t]*output[t][b][d] (f32 out) ----------------
__global__ __launch_bounds__(256) void pool_kernel(
    const float* __restrict__ attnw, const ushort_t* __restrict__ output,
    float* __restrict__ pooled) {
  __shared__ float at[256];
  int bi = blockIdx.x;
  int b = bi >> 1, half = bi & 1;
  int tid = threadIdx.x;
  at[tid] = scrub(attnw[(size_t)b * 256 + tid]);
  __syncthreads();
  int d0 = half * 512 + tid * 2;
  float a0 = 0.f, a1 = 0.f;
  for (int t = 0; t < 256; ++t) {
    uint_t u = *(const uint_t*)&output[(size_t)t * 131072 + (size_t)b * 1024 + d0];
    float w = at[t];
    a0 += w * scrub(bf2f((ushort_t)(u & 0xffffu)));
    a1 += w * scrub(bf2f((ushort_t)(u >> 16)));
  }
  *(f32x2*)&pooled[(size_t)b * 1024 + d0] = (f32x2){a0, a1};
}

extern "C" void kernel_launch(void* const* d_in, const int* in_sizes, int n_in,
                              void* d_out, int out_size, void* d_ws, size_t ws_size,
                              hipStream_t stream) {
  (void)in_sizes; (void)n_in; (void)out_size;
  const int*   tim_seq = (const int*)d_in[0];
  const int*   loc_seq = (const int*)d_in[1];
  const float* state   = (const float*)d_in[2];
  const float* emb_tim = (const float*)d_in[3];
  const float* emb_loc = (const float*)d_in[4];
  const float* Wih_f   = (const float*)d_in[5];
  const float* Whh_f   = (const float*)d_in[6];
  const float* bih_f   = (const float*)d_in[7];
  const float* bhh_f   = (const float*)d_in[8];
  const float* Wih_b   = (const float*)d_in[9];
  const float* Whh_b   = (const float*)d_in[10];
  const float* bih_b   = (const float*)d_in[11];
  const float* bhh_b   = (const float*)d_in[12];
  const float* W_att   = (const float*)d_in[13];
  const float* b_att   = (const float*)d_in[14];
  const float* w_proj  = (const float*)d_in[15];
  float* out = (float*)d_out;   // [pooled 131072][state 131072][attn 32768] f32

  // Workspace layout (~70.4 MB; verified available)
  char* ws = (char*)d_ws;
  float*    scores = (float*)   (ws);                   //   131,072 B
  uint_t*   flags  = (uint_t*)  (ws + 131072);          //     4,096 B ([16][64] u32)
  uint_t*   h2     = (uint_t*)  (ws + 135168);          // 1,048,576 B
  ushort_t* WattT  = (ushort_t*)(ws + 1183744);         // 2,097,152 B
  ushort_t* output = (ushort_t*)(ws + 3280896);         // 67,108,864 B
  const size_t NEED = 3280896 + 67108864;
  if (ws_size < NEED) return;

  zero_kernel<<<4, 256, 0, stream>>>(flags, 1024);   // zero all per-chain flags

  init_kernel<<<512, 256, 0, stream>>>(state, h2);
  transpose_kernel<<<1024, 256, 0, stream>>>(W_att, WattT);

  rnn_kernel<<<128, 512, 0, stream>>>(tim_seq, loc_seq, emb_tim, emb_loc, state,
                                      h2,
                                      Wih_f, Whh_f, bih_f, bhh_f,
                                      Wih_b, Whh_b, bih_b, bhh_b,
                                      output, out + 131072, flags);

  score_kernel<<<256, 256, 0, stream>>>(output, WattT, b_att, w_proj, scores);
  softmax_kernel<<<128, 256, 0, stream>>>(scores, out + 262144);
  pool_kernel<<<256, 256, 0, stream>>>(out + 262144, output, out);
}

// Round 19
// 3446.943 us; speedup vs baseline: 1.6763x; 1.6763x over previous
//
#include <hip/hip_runtime.h>

typedef unsigned short ushort_t;
typedef unsigned int   uint_t;
typedef unsigned long long u64;
using bf16x8 = __attribute__((ext_vector_type(8))) short;
using f32x4  = __attribute__((ext_vector_type(4))) float;
using f32x2  = __attribute__((ext_vector_type(2))) float;

// T=256, B=128, H=512, E=256, IN=512, D=1024, 3H=1536.  ALL float I/O is FP32.

__device__ __forceinline__ float bf2f(ushort_t u) {
  union { uint_t i; float f; } v; v.i = ((uint_t)u) << 16; return v.f;
}
__device__ __forceinline__ ushort_t f2bf(float f) {
  union { float f; uint_t i; } v; v.f = f;
  uint_t r = v.i + 0x7fffu + ((v.i >> 16) & 1u);
  return (ushort_t)(r >> 16);
}
__device__ __forceinline__ float scrub(float x) {
  union { float f; uint_t i; } v; v.f = x;
  return ((v.i & 0x7f800000u) == 0x7f800000u) ? 0.f : x;
}
__device__ __forceinline__ float sclamp(float x) {
  float y = scrub(x);
  return fminf(30.f, fmaxf(-30.f, y));
}
__device__ __forceinline__ float sigm(float x) { return 1.f / (1.f + __expf(-x)); }
__device__ __forceinline__ float tanh_f(float x) {
  float t = __expf(-2.f * fabsf(x));
  float r = (1.f - t) / (1.f + t);
  return x < 0.f ? -r : r;
}
// load 8 f32 and convert to bf16x8 (RNE)
__device__ __forceinline__ bf16x8 cvt8(const float* __restrict__ p) {
  f32x4 u0 = *(const f32x4*)p;
  f32x4 u1 = *(const f32x4*)(p + 4);
  bf16x8 r;
  #pragma unroll
  for (int j = 0; j < 4; ++j) { r[j] = (short)f2bf(u0[j]); r[j+4] = (short)f2bf(u1[j]); }
  return r;
}

// ---------------- zero-fill ----------------
__global__ __launch_bounds__(256) void zero_kernel(uint_t* __restrict__ p, int n32) {
  int i = blockIdx.x * 256 + threadIdx.x;
  if (i < n32) p[i] = 0;
}

// ---------------- init h2 (hi|lo packed bf16 split of f32 state), both parities ----------------
__global__ __launch_bounds__(256) void init_kernel(
    const float* __restrict__ state, uint_t* __restrict__ h2) {
  int i = blockIdx.x * 256 + threadIdx.x;   // 0..131071 over (2,128,512)
  float v = state[i];
  ushort_t hi = f2bf(v);
  ushort_t lo = f2bf(v - bf2f(hi));
  uint_t packed = ((uint_t)hi << 16) | (uint_t)lo;
  int dirp = i >> 16;
  int rem  = i & 65535;
  h2[(size_t)(dirp * 2 + 0) * 65536 + rem] = packed;
  h2[(size_t)(dirp * 2 + 1) * 65536 + rem] = packed;
}

// ---------------- transpose W_att (f32 1024x1024) -> WattT bf16 [j][d] ----------------
__global__ __launch_bounds__(256) void transpose_kernel(
    const float* __restrict__ W, ushort_t* __restrict__ WT) {
  __shared__ float tile[32][33];
  int bx = blockIdx.x & 31, by = blockIdx.x >> 5;
  int r0 = by * 32, c0 = bx * 32;
  int tid = threadIdx.x;
  int r = tid >> 3, c4 = (tid & 7) * 4;
  #pragma unroll
  for (int i = 0; i < 4; ++i) tile[r][c4 + i] = W[(size_t)(r0 + r) * 1024 + c0 + c4 + i];
  __syncthreads();
  int jr = tid >> 3, d4 = (tid & 7) * 4;
  #pragma unroll
  for (int i = 0; i < 4; ++i)
    WT[(size_t)(c0 + jr) * 1024 + r0 + d4 + i] = f2bf(tile[d4 + i][jr]);
}

// ---------------- the recurrent kernel (R17 k-split structure + ILP fixes) ----------------
// grid = 128 blocks (blockIdx = wg*4 + dirgroup), 512 threads (8 waves), 1 block/CU.
// Wave (rg = w&3, kh = w>>2) computes rows [rg*16,+16) x cols [wg*16,+16) for
// k in [kh*256,+256) of both GEMMs; partials combined via LDS (2 phases, 3 barriers).
// kh0 waves do elementwise + h2 stores + release (proven R12/R17 protocol).
// R19 deltas vs R17 (arithmetic-identical): (1) h-MFMA issued PLANE-MAJOR so each
// accumulator's dependent ops are 3 apart (was 3 back-to-back); (2) x rows converted
// to bf16 at PREFETCH time (cvt off the serial x-phase; px halved to 8 registers).
__global__ __launch_bounds__(512, 2) void rnn_kernel(
    const int* __restrict__ tim_seq, const int* __restrict__ loc_seq,
    const float* __restrict__ emb_tim, const float* __restrict__ emb_loc,
    const float* __restrict__ state,        // [2][128][512] f32 (h0)
    uint_t* __restrict__ h2,                // [2dir][2par][128][512] u32 (hi|lo)
    const float* __restrict__ Wih_f, const float* __restrict__ Whh_f,
    const float* __restrict__ bih_f, const float* __restrict__ bhh_f,
    const float* __restrict__ Wih_b, const float* __restrict__ Whh_b,
    const float* __restrict__ bih_b, const float* __restrict__ bhh_b,
    ushort_t* __restrict__ output,          // [256][128][1024] bf16 (intermediate)
    float* __restrict__ state_out,          // d_out + 131072 : [2][128][512] f32
    uint_t* __restrict__ flags)             // [4][4][32] per-chain step flags
{
  __shared__ __align__(16) ushort_t Wxh[48 * 512];     // Wih hi      49,152 B
  __shared__ __align__(16) ushort_t Whi[48 * 512];     // Whh hi      49,152 B
  __shared__ __align__(16) ushort_t Wlo[48 * 512];     // Whh lo      49,152 B
  __shared__ float comb[4][64][9];                     //  9,216 B
  __shared__ float bias_l[6][16];                      //    384 B

  const int tid  = threadIdx.x;
  const int lane = tid & 63;
  const int wave = tid >> 6;           // 0..7
  const int rg   = wave & 3;           // row group
  const int kh   = wave >> 2;          // k half (0: k<256 -> tim, 1: k>=256 -> loc)
  const int bi   = blockIdx.x;
  const int dirgroup = bi & 3;
  const int wg   = bi >> 2;            // 0..31
  const int dir  = dirgroup >> 1;
  const int grp  = dirgroup & 1;
  const int b0   = grp * 64;
  uint_t* chain_flags = flags + (dirgroup * 4 + rg) * 32;

  const float* Wih = dir ? Wih_b : Wih_f;
  const float* Whh = dir ? Whh_b : Whh_f;
  const float* bih = dir ? bih_b : bih_f;
  const float* bhh = dir ? bhh_b : bhh_f;

  // stage weights: Wih->hi only; Whh->hi+lo. XOR-swizzled k per gate row.
  for (int c = tid; c < 6144; c += 512) {   // 2 mats * 48 rows * 64 chunks
    int m = c >= 3072 ? 1 : 0;
    int cc = c - m * 3072;
    int gcl = cc >> 6;
    int k8  = (cc & 63) << 3;
    int grow = (gcl >> 4) * 512 + wg * 16 + (gcl & 15);
    const float* src = (m ? Whh : Wih) + (size_t)grow * 512 + k8;
    f32x4 u0 = *(const f32x4*)src;
    f32x4 u1 = *(const f32x4*)(src + 4);
    bf16x8 hi8, lo8;
    #pragma unroll
    for (int j = 0; j < 8; ++j) {
      float v = j < 4 ? u0[j] : u1[j - 4];
      ushort_t h = f2bf(v);
      hi8[j] = (short)h;
      lo8[j] = (short)f2bf(v - bf2f(h));
    }
    int dst = gcl * 512 + (k8 ^ ((gcl & 7) << 3));
    if (m) { *(bf16x8*)&Whi[dst] = hi8; *(bf16x8*)&Wlo[dst] = lo8; }
    else   { *(bf16x8*)&Wxh[dst] = hi8; }
  }
  if (tid < 96) {
    int m  = tid / 48;
    int gg = (tid % 48) / 16;
    int c  = tid & 15;
    const float* bb = m ? bhh : bih;
    bias_l[m * 3 + gg][c] = bb[gg * 512 + wg * 16 + c];
  }

  const int rlane = lane & 15;
  const int klb   = (lane >> 4) * 8;   // per-lane k sub-offset
  const int qrow  = (lane >> 4) * 4;
  const int arow  = b0 + rg * 16 + rlane;
  const int kb0   = kh * 256;          // this wave's k-half base
  const int swz   = (rlane & 7) << 3;

  float hp[4] = {0.f, 0.f, 0.f, 0.f};
  if (kh == 0) {
    #pragma unroll
    for (int q = 0; q < 4; ++q)
      hp[q] = state[(size_t)dir * 65536 + (size_t)(b0 + rg * 16 + qrow + q) * 512 +
                    wg * 16 + rlane];
  }
  __syncthreads();

  // embedding source for this wave's k-half
  const int*   seq  = kh ? loc_seq : tim_seq;
  const float* etab = kh ? emb_loc : emb_tim;

  // ---- prefetch next-step x rows as bf16 (8 chunks, cvt at prefetch) ----
  bf16x8 px[8];
  {
    const int td0 = dir ? 255 : 0;
    const float* base = etab + (size_t)seq[td0 * 128 + arow] * 256;
    #pragma unroll
    for (int kk = 0; kk < 8; ++kk) px[kk] = cvt8(base + kk * 32 + klb);
  }

  uint_t pv = (lane < 32) ? 0u : 0xFFFFFFFFu;   // persistent poll register

  for (int t = 0; t < 256; ++t) {
    const int td  = dir ? (255 - t) : t;
    const int par = t & 1;

    f32x4 ar  = {0.f, 0.f, 0.f, 0.f};
    f32x4 az  = {0.f, 0.f, 0.f, 0.f};
    f32x4 axn = {0.f, 0.f, 0.f, 0.f};
    f32x4 ahn = {0.f, 0.f, 0.f, 0.f};

    // ---- 1. x-MFMA from prefetched bf16 registers (8 kk, this k-half) ----
    #pragma unroll
    for (int kk = 0; kk < 8; ++kk) {
      int k = kb0 + kk * 32 + klb;
      int o0 = (0 * 16 + rlane) * 512 + (k ^ swz);
      int o1 = (1 * 16 + rlane) * 512 + (k ^ swz);
      int o2 = (2 * 16 + rlane) * 512 + (k ^ swz);
      ar  = __builtin_amdgcn_mfma_f32_16x16x32_bf16(px[kk], *(const bf16x8*)&Wxh[o0], ar,  0, 0, 0);
      az  = __builtin_amdgcn_mfma_f32_16x16x32_bf16(px[kk], *(const bf16x8*)&Wxh[o1], az,  0, 0, 0);
      axn = __builtin_amdgcn_mfma_f32_16x16x32_bf16(px[kk], *(const bf16x8*)&Wxh[o2], axn, 0, 0, 0);
    }

    // ---- 2. issue next step's gather prefetch (overlaps poll + h phase) ----
    if (t < 255) {
      const int tdn = dir ? (255 - (t + 1)) : (t + 1);
      const float* base = etab + (size_t)seq[tdn * 128 + arow] * 256;
      #pragma unroll
      for (int kk = 0; kk < 8; ++kk) px[kk] = cvt8(base + kk * 32 + klb);
    }

    // ---- 3. poll chain flags (early-check persistent register, fine sleep) ----
    while (!__all(pv >= (uint_t)t)) {
      if (lane < 32)
        pv = __hip_atomic_load(&chain_flags[lane], __ATOMIC_RELAXED,
                               __HIP_MEMORY_SCOPE_AGENT);
      if (__all(pv >= (uint_t)t)) break;
      __builtin_amdgcn_s_sleep(2);
    }
    asm volatile("" ::: "memory");

    // ---- 4. h-loads + h-MFMA, PLANE-MAJOR issue (per-acc ops 3 apart) ----
    {
      const u64* hrow = (const u64*)(h2 + (size_t)(dir * 2 + par) * 65536 +
                                     (size_t)arow * 512);
      #pragma unroll
      for (int kk = 0; kk < 8; ++kk) {
        int k = kb0 + kk * 32 + klb;
        u64 q0 = __hip_atomic_load(hrow + (k >> 1),     __ATOMIC_RELAXED, __HIP_MEMORY_SCOPE_AGENT);
        u64 q1 = __hip_atomic_load(hrow + (k >> 1) + 1, __ATOMIC_RELAXED, __HIP_MEMORY_SCOPE_AGENT);
        u64 q2 = __hip_atomic_load(hrow + (k >> 1) + 2, __ATOMIC_RELAXED, __HIP_MEMORY_SCOPE_AGENT);
        u64 q3 = __hip_atomic_load(hrow + (k >> 1) + 3, __ATOMIC_RELAXED, __HIP_MEMORY_SCOPE_AGENT);
        uint_t w[8] = { (uint_t)q0, (uint_t)(q0 >> 32), (uint_t)q1, (uint_t)(q1 >> 32),
                        (uint_t)q2, (uint_t)(q2 >> 32), (uint_t)q3, (uint_t)(q3 >> 32) };
        bf16x8 ahi, alo;
        #pragma unroll
        for (int j = 0; j < 8; ++j) {
          ahi[j] = (short)(w[j] >> 16);
          alo[j] = (short)(w[j] & 0xffffu);
        }
        int o0 = (0 * 16 + rlane) * 512 + (k ^ swz);
        int o1 = (1 * 16 + rlane) * 512 + (k ^ swz);
        int o2 = (2 * 16 + rlane) * 512 + (k ^ swz);
        bf16x8 bh0 = *(const bf16x8*)&Whi[o0], bl0 = *(const bf16x8*)&Wlo[o0];
        bf16x8 bh1 = *(const bf16x8*)&Whi[o1], bl1 = *(const bf16x8*)&Wlo[o1];
        bf16x8 bh2 = *(const bf16x8*)&Whi[o2], bl2 = *(const bf16x8*)&Wlo[o2];
        // plane hh
        ar  = __builtin_amdgcn_mfma_f32_16x16x32_bf16(ahi, bh0, ar,  0, 0, 0);
        az  = __builtin_amdgcn_mfma_f32_16x16x32_bf16(ahi, bh1, az,  0, 0, 0);
        ahn = __builtin_amdgcn_mfma_f32_16x16x32_bf16(ahi, bh2, ahn, 0, 0, 0);
        // plane lh
        ar  = __builtin_amdgcn_mfma_f32_16x16x32_bf16(alo, bh0, ar,  0, 0, 0);
        az  = __builtin_amdgcn_mfma_f32_16x16x32_bf16(alo, bh1, az,  0, 0, 0);
        ahn = __builtin_amdgcn_mfma_f32_16x16x32_bf16(alo, bh2, ahn, 0, 0, 0);
        // plane hl
        ar  = __builtin_amdgcn_mfma_f32_16x16x32_bf16(ahi, bl0, ar,  0, 0, 0);
        az  = __builtin_amdgcn_mfma_f32_16x16x32_bf16(ahi, bl1, az,  0, 0, 0);
        ahn = __builtin_amdgcn_mfma_f32_16x16x32_bf16(ahi, bl2, ahn, 0, 0, 0);
      }
    }

    // ---- 5. combine k-halves via LDS (2 phases, disjoint in time) ----
    if (kh == 1) {
      #pragma unroll
      for (int q = 0; q < 4; ++q) {
        comb[rg][lane][q]     = ar[q];
        comb[rg][lane][4 + q] = az[q];
      }
    }
    __syncthreads();
    if (kh == 0) {
      #pragma unroll
      for (int q = 0; q < 4; ++q) {
        ar[q] += comb[rg][lane][q];
        az[q] += comb[rg][lane][4 + q];
      }
    }
    __syncthreads();
    if (kh == 1) {
      #pragma unroll
      for (int q = 0; q < 4; ++q) {
        comb[rg][lane][q]     = axn[q];
        comb[rg][lane][4 + q] = ahn[q];
      }
    }
    __syncthreads();

    // ---- 6. elementwise + stores + release (kh0 waves only) ----
    if (kh == 0) {
      #pragma unroll
      for (int q = 0; q < 4; ++q) {
        axn[q] += comb[rg][lane][q];
        ahn[q] += comb[rg][lane][4 + q];
      }
      ushort_t hh_out[4];
      const float bir = bias_l[0][rlane], biz = bias_l[1][rlane], bin_ = bias_l[2][rlane];
      const float bhr = bias_l[3][rlane], bhz = bias_l[4][rlane], bhn_ = bias_l[5][rlane];
      const size_t hnew = (size_t)(dir * 2 + (par ^ 1)) * 65536;
      #pragma unroll
      for (int q = 0; q < 4; ++q) {
        int row = b0 + rg * 16 + qrow + q;
        float r = sigm(sclamp(ar[q] + bir + bhr));
        float z = sigm(sclamp(az[q] + biz + bhz));
        float n = tanh_f(sclamp(axn[q] + bin_) + r * sclamp(ahn[q] + bhn_));
        float hn = (1.f - z) * n + z * hp[q];
        hp[q] = hn;
        ushort_t hh = f2bf(hn);
        ushort_t hl = f2bf(hn - bf2f(hh));
        hh_out[q] = hh;
        __hip_atomic_store(&h2[hnew + (size_t)row * 512 + wg * 16 + rlane],
                           ((uint_t)hh << 16) | (uint_t)hl,
                           __ATOMIC_RELAXED, __HIP_MEMORY_SCOPE_AGENT);
      }
      asm volatile("s_waitcnt vmcnt(0)" ::: "memory");
      if (t < 255 && lane == 0) {
        __hip_atomic_store(&chain_flags[wg], (uint_t)(t + 1),
                           __ATOMIC_RELAXED, __HIP_MEMORY_SCOPE_AGENT);
      }
      asm volatile("" ::: "memory");
      #pragma unroll
      for (int q = 0; q < 4; ++q) {
        int row = b0 + rg * 16 + qrow + q;
        output[(size_t)td * 131072 + (size_t)row * 1024 + dir * 512 + wg * 16 + rlane] =
            hh_out[q];
        if (t == 255) {
          state_out[(size_t)dir * 65536 + (size_t)row * 512 + wg * 16 + rlane] = hp[q];
        }
      }
    }

    // ---- 7. refresh poll register (after release; used next iteration) ----
    if (t < 255 && lane < 32)
      pv = __hip_atomic_load(&chain_flags[lane], __ATOMIC_RELAXED,
                             __HIP_MEMORY_SCOPE_AGENT);
  }
}

// ---------------- fused attention scores ----------------
__global__ __launch_bounds__(256) void score_kernel(
    const ushort_t* __restrict__ output,   // [32768][1024] bf16
    const ushort_t* __restrict__ WattT,    // [1024][1024] bf16 (j, d)
    const float* __restrict__ b_att, const float* __restrict__ w_proj,
    float* __restrict__ scores)            // [128][256]
{
  __shared__ __align__(16) ushort_t bst[2][128][72];
  __shared__ float scl[128];
  const int tid = threadIdx.x, lane = tid & 63, wave = tid >> 6;
  const int tb0 = blockIdx.x * 128;
  if (tid < 128) scl[tid] = 0.f;
  __syncthreads();

  const int rlane = lane & 15;
  const int kbase = (lane >> 4) * 8;
  const int sjrow = tid >> 2;
  const int sq8   = (tid & 3) * 8;

  for (int jc = 0; jc < 8; ++jc) {
    f32x4 acc[2][8];
    #pragma unroll
    for (int rt = 0; rt < 2; ++rt)
      #pragma unroll
      for (int ct = 0; ct < 8; ++ct) acc[rt][ct] = (f32x4){0.f, 0.f, 0.f, 0.f};

    {
      const size_t base = (size_t)(jc * 128) * 1024 + sq8;
      *(bf16x8*)&bst[0][sjrow][sq8] = *(const bf16x8*)(WattT + base + (size_t)sjrow * 1024);
      *(bf16x8*)&bst[0][sjrow + 64][sq8] = *(const bf16x8*)(WattT + base + (size_t)(sjrow + 64) * 1024);
    }
    __syncthreads();

    for (int kc = 0; kc < 32; ++kc) {
      if (kc < 31) {
        const size_t base = (size_t)(jc * 128) * 1024 + (size_t)(kc + 1) * 32 + sq8;
        *(bf16x8*)&bst[(kc + 1) & 1][sjrow][sq8] =
            *(const bf16x8*)(WattT + base + (size_t)sjrow * 1024);
        *(bf16x8*)&bst[(kc + 1) & 1][sjrow + 64][sq8] =
            *(const bf16x8*)(WattT + base + (size_t)(sjrow + 64) * 1024);
      }
      int r0 = wave * 32 + rlane;
      int k = kc * 32 + kbase;
      bf16x8 a0 = *(const bf16x8*)(output + (size_t)(tb0 + r0) * 1024 + k);
      bf16x8 a1 = *(const bf16x8*)(output + (size_t)(tb0 + r0 + 16) * 1024 + k);
      int buf = kc & 1;
      #pragma unroll
      for (int ct = 0; ct < 8; ++ct) {
        bf16x8 b = *(const bf16x8*)&bst[buf][ct * 16 + rlane][kbase];
        acc[0][ct] = __builtin_amdgcn_mfma_f32_16x16x32_bf16(a0, b, acc[0][ct], 0, 0, 0);
        acc[1][ct] = __builtin_amdgcn_mfma_f32_16x16x32_bf16(a1, b, acc[1][ct], 0, 0, 0);
      }
      __syncthreads();
    }

    float s[2][4] = {{0.f, 0.f, 0.f, 0.f}, {0.f, 0.f, 0.f, 0.f}};
    #pragma unroll
    for (int ct = 0; ct < 8; ++ct) {
      int j = jc * 128 + ct * 16 + rlane;
      float bv = b_att[j];
      float wv = w_proj[j];
      #pragma unroll
      for (int rt = 0; rt < 2; ++rt)
        #pragma unroll
        for (int q = 0; q < 4; ++q)
          s[rt][q] += tanh_f(sclamp(acc[rt][ct][q] + bv)) * wv;
    }
    #pragma unroll
    for (int rt = 0; rt < 2; ++rt)
      #pragma unroll
      for (int q = 0; q < 4; ++q) {
        float v = s[rt][q];
        v += __shfl_xor(v, 1, 64);
        v += __shfl_xor(v, 2, 64);
        v += __shfl_xor(v, 4, 64);
        v += __shfl_xor(v, 8, 64);
        if ((lane & 15) == 0)
          scl[wave * 32 + rt * 16 + (lane >> 4) * 4 + q] += v;
      }
  }
  __syncthreads();
  if (tid < 128) {
    int tb = tb0 + tid;
    scores[(size_t)(tb & 127) * 256 + (tb >> 7)] = scrub(scl[tid]);
  }
}

// ---------------- softmax over t per batch row (f32 out) ----------------
__global__ __launch_bounds__(256) void softmax_kernel(
    const float* __restrict__ scores, float* __restrict__ attn_out) {
  __shared__ float red[4];
  int b = blockIdx.x, tid = threadIdx.x, lane = tid & 63, wave = tid >> 6;
  float v = scrub(scores[(size_t)b * 256 + tid]);
  float mx = v;
  #pragma unroll
  for (int o = 1; o < 64; o <<= 1) mx = fmaxf(mx, __shfl_xor(mx, o, 64));
  if (lane == 0) red[wave] = mx;
  __syncthreads();
  mx = fmaxf(fmaxf(red[0], red[1]), fmaxf(red[2], red[3]));
  float e = __expf(v - mx);
  float s = e;
  #pragma unroll
  for (int o = 1; o < 64; o <<= 1) s += __shfl_xor(s, o, 64);
  __syncthreads();
  if (lane == 0) red[wave] = s;
  __syncthreads();
  s = red[0] + red[1] + red[2] + red[3];
  attn_out[(size_t)b * 256 + tid] = e / s;
}

// ---------------- pooled[b][d] = sum_t attn[b][t]*output[t][b][d] (f32 out) ----------------
__global__ __launch_bounds__(256) void pool_kernel(
    const float* __restrict__ attnw, const ushort_t* __restrict__ output,
    float* __restrict__ pooled) {
  __shared__ float at[256];
  int bi = blockIdx.x;
  int b = bi >> 1, half = bi & 1;
  int tid = threadIdx.x;
  at[tid] = scrub(attnw[(size_t)b * 256 + tid]);
  __syncthreads();
  int d0 = half * 512 + tid * 2;
  float a0 = 0.f, a1 = 0.f;
  for (int t = 0; t < 256; ++t) {
    uint_t u = *(const uint_t*)&output[(size_t)t * 131072 + (size_t)b * 1024 + d0];
    float w = at[t];
    a0 += w * scrub(bf2f((ushort_t)(u & 0xffffu)));
    a1 += w * scrub(bf2f((ushort_t)(u >> 16)));
  }
  *(f32x2*)&pooled[(size_t)b * 1024 + d0] = (f32x2){a0, a1};
}

extern "C" void kernel_launch(void* const* d_in, const int* in_sizes, int n_in,
                              void* d_out, int out_size, void* d_ws, size_t ws_size,
                              hipStream_t stream) {
  (void)in_sizes; (void)n_in; (void)out_size;
  const int*   tim_seq = (const int*)d_in[0];
  const int*   loc_seq = (const int*)d_in[1];
  const float* state   = (const float*)d_in[2];
  const float* emb_tim = (const float*)d_in[3];
  const float* emb_loc = (const float*)d_in[4];
  const float* Wih_f   = (const float*)d_in[5];
  const float* Whh_f   = (const float*)d_in[6];
  const float* bih_f   = (const float*)d_in[7];
  const float* bhh_f   = (const float*)d_in[8];
  const float* Wih_b   = (const float*)d_in[9];
  const float* Whh_b   = (const float*)d_in[10];
  const float* bih_b   = (const float*)d_in[11];
  const float* bhh_b   = (const float*)d_in[12];
  const float* W_att   = (const float*)d_in[13];
  const float* b_att   = (const float*)d_in[14];
  const float* w_proj  = (const float*)d_in[15];
  float* out = (float*)d_out;   // [pooled 131072][state 131072][attn 32768] f32

  // Workspace layout (~70.4 MB; verified available)
  char* ws = (char*)d_ws;
  float*    scores = (float*)   (ws);                   //   131,072 B
  uint_t*   flags  = (uint_t*)  (ws + 131072);          //     2,048 B ([4][4][32] u32)
  uint_t*   h2     = (uint_t*)  (ws + 135168);          // 1,048,576 B
  ushort_t* WattT  = (ushort_t*)(ws + 1183744);         // 2,097,152 B
  ushort_t* output = (ushort_t*)(ws + 3280896);         // 67,108,864 B
  const size_t NEED = 3280896 + 67108864;
  if (ws_size < NEED) return;

  zero_kernel<<<2, 256, 0, stream>>>(flags, 512);   // zero all per-chain flags

  init_kernel<<<512, 256, 0, stream>>>(state, h2);
  transpose_kernel<<<1024, 256, 0, stream>>>(W_att, WattT);

  rnn_kernel<<<128, 512, 0, stream>>>(tim_seq, loc_seq, emb_tim, emb_loc, state,
                                      h2,
                                      Wih_f, Whh_f, bih_f, bhh_f,
                                      Wih_b, Whh_b, bih_b, bhh_b,
                                      output, out + 131072, flags);

  score_kernel<<<256, 256, 0, stream>>>(output, WattT, b_att, w_proj, scores);
  softmax_kernel<<<128, 256, 0, stream>>>(scores, out + 262144);
  pool_kernel<<<256, 256, 0, stream>>>(out + 262144, output, out);
}